// Round 1
// baseline (323.389 us; speedup 1.0000x reference)
//
#include <hip/hip_runtime.h>

// Roformer MHA: T=2048 B=2 E=1024 H=16 HD=64
#define T_  2048
#define B_  2
#define E_  1024
#define H_  16
#define HD_ 64
#define M_  4096          // T*B rows
#define N_QKV 3072        // 3*E

typedef unsigned short u16;
typedef unsigned int   u32;
typedef __attribute__((ext_vector_type(8))) __bf16 bf16x8;
typedef __attribute__((ext_vector_type(4))) float  f32x4;

__device__ inline u16 f2bf(float f) {
  u32 u = __float_as_uint(f);
  u += 0x7fffu + ((u >> 16) & 1u);   // RTNE (finite values)
  return (u16)(u >> 16);
}

__device__ inline void gl_lds16(const u16* g, u16* l) {
  __builtin_amdgcn_global_load_lds(
      (const __attribute__((address_space(1))) u32*)g,
      (__attribute__((address_space(3))) u32*)l, 16, 0, 0);
}

// ---------------- Pass A: fp32 -> bf16 conversion --------------------------
__global__ __launch_bounds__(256) void cvt_kernel(
    const float* __restrict__ q, const float* __restrict__ wi,
    const float* __restrict__ wo, u16* __restrict__ X,
    u16* __restrict__ Wi, u16* __restrict__ Wo) {
  int idx = blockIdx.x * 256 + threadIdx.x;       // one float4 per thread
  const int n1 = (M_ * E_) / 4, n2 = (3 * E_ * E_) / 4;
  const float4* src; u16* dst; int i;
  if (idx < n1)            { src = (const float4*)q;  dst = X;  i = idx; }
  else if (idx < n1 + n2)  { src = (const float4*)wi; dst = Wi; i = idx - n1; }
  else                     { src = (const float4*)wo; dst = Wo; i = idx - n1 - n2; }
  float4 v = src[i];
  uint2 o;
  o.x = (u32)f2bf(v.x) | ((u32)f2bf(v.y) << 16);
  o.y = (u32)f2bf(v.z) | ((u32)f2bf(v.w) << 16);
  *(uint2*)&dst[(size_t)i * 4] = o;
}

// ---------------- Pass B: QKV GEMM + bias + scale + RoPE + scatter ---------
// C[m][n] = sum_e X[m][e] * W[n][e],  M=4096, N=3072, K=1024
__global__ __launch_bounds__(256) void gemm_qkv(
    const u16* __restrict__ X, const u16* __restrict__ W,
    const float* __restrict__ bias, const float* __restrict__ rel,
    u16* __restrict__ qb, u16* __restrict__ kb, u16* __restrict__ vr) {
  const int K = E_;
  __shared__ u16 As[128 * 32];
  __shared__ u16 Bs[128 * 32];
  const int tm = blockIdx.x * 128, tn = blockIdx.y * 128;
  const int tid = threadIdx.x;
  const int w = tid >> 6, lane = tid & 63, lr = lane & 15, lg = lane >> 4;
  const int wm = (w >> 1) * 64, wn = (w & 1) * 64;
  f32x4 acc[4][4] = {};
  for (int k0 = 0; k0 < K; k0 += 32) {
    #pragma unroll
    for (int hh = 0; hh < 2; ++hh) {
      int ca = (w * 2 + hh) * 64 + lane;           // 16B chunk index 0..511
      gl_lds16(X + (size_t)(tm + (ca >> 2)) * K + k0 + (ca & 3) * 8,
               &As[(w * 2 + hh) * 512]);
      gl_lds16(W + (size_t)(tn + (ca >> 2)) * K + k0 + (ca & 3) * 8,
               &Bs[(w * 2 + hh) * 512]);
    }
    __syncthreads();
    bf16x8 af[4], bq[4];
    #pragma unroll
    for (int mi = 0; mi < 4; ++mi)
      af[mi] = *(const bf16x8*)&As[(wm + mi * 16 + lr) * 32 + lg * 8];
    #pragma unroll
    for (int ni = 0; ni < 4; ++ni)
      bq[ni] = *(const bf16x8*)&Bs[(wn + ni * 16 + lr) * 32 + lg * 8];
    #pragma unroll
    for (int mi = 0; mi < 4; ++mi)
      #pragma unroll
      for (int ni = 0; ni < 4; ++ni)
        acc[mi][ni] = __builtin_amdgcn_mfma_f32_16x16x32_bf16(
            af[mi], bq[ni], acc[mi][ni], 0, 0, 0);
    __syncthreads();
  }
  // epilogue: bias, q-scale, RoPE(q,k), scatter to [bh][t][hd]
  #pragma unroll
  for (int ni = 0; ni < 4; ++ni) {
    int n = tn + wn + ni * 16 + lr;
    float bv = bias[n];
    int sect = n >> 10, nn = n & 1023;
    int h = nn >> 6, d = nn & 63, i2 = d >> 1;
    u16* dst = (sect == 0) ? qb : (sect == 1) ? kb : vr;
    #pragma unroll
    for (int mi = 0; mi < 4; ++mi) {
      #pragma unroll
      for (int r = 0; r < 4; ++r) {
        int m = tm + wm + mi * 16 + lg * 4 + r;
        int t = m >> 1, bb = m & 1;
        float v = acc[mi][ni][r] + bv;
        if (sect == 0) v *= 0.125f;                 // HD^-0.5
        if (sect < 2) {                             // RoPE (uniform branch)
          float partner = __shfl_xor(v, 1);
          float sp = rel[t * HD_ + i2];
          float cp = rel[t * HD_ + 32 + i2];
          float rot = (d & 1) ? partner : -partner;
          v = v * cp + rot * sp;
        }
        dst[((size_t)(bb * H_ + h) * T_ + t) * HD_ + d] = f2bf(v);
      }
    }
  }
}

// ---------------- Pass C: V transpose [bh][t][d] -> [bh][d][t] -------------
__global__ __launch_bounds__(256) void vtrans(
    const u16* __restrict__ vr, u16* __restrict__ vt) {
  __shared__ u16 tile[64][80];
  int bh = blockIdx.y, t0 = blockIdx.x * 64;
  int tid = threadIdx.x;
  int row = tid >> 2, c0 = (tid & 3) * 16;
  const u16* src = vr + ((size_t)bh * T_ + t0) * HD_;
  uint4 a = *(const uint4*)&src[row * HD_ + c0];
  uint4 b = *(const uint4*)&src[row * HD_ + c0 + 8];
  *(uint4*)&tile[row][c0] = a;
  *(uint4*)&tile[row][c0 + 8] = b;
  __syncthreads();
  int dr = tid >> 2, tc = (tid & 3) * 16;
  __align__(16) u16 vals[16];
  #pragma unroll
  for (int i = 0; i < 16; ++i) vals[i] = tile[tc + i][dr];
  u16* dstp = vt + ((size_t)bh * HD_ + dr) * T_ + t0 + tc;
  *(uint4*)&dstp[0] = *(uint4*)&vals[0];
  *(uint4*)&dstp[8] = *(uint4*)&vals[8];
}

// ---------------- Pass D: flash attention ----------------------------------
// grid (T/64, BH); 4 waves, each owns 16 q rows.
// Swapped QK^T: St = mfma(K, Q^T) so softmax row is lane-local-ish (reduce over lg).
#define PSW(lr, e) ((e) ^ (((lr) & 7) << 3))        // LDS bank swizzle (elems)
__global__ __launch_bounds__(256) void attn_kernel(
    const u16* __restrict__ qbm, const u16* __restrict__ kbm,
    const u16* __restrict__ vtm, u16* __restrict__ attnb) {
  int bh = blockIdx.y;
  int tid = threadIdx.x;
  int w = tid >> 6, lane = tid & 63, lr = lane & 15, lg = lane >> 4;
  int qbase = blockIdx.x * 64 + w * 16;
  __shared__ u16 Pl[4][16][64];
  const u16* qrow = qbm + (size_t)bh * T_ * HD_;
  const u16* krow = kbm + (size_t)bh * T_ * HD_;
  const u16* vrow = vtm + (size_t)bh * HD_ * T_;
  bf16x8 qf[2];
  #pragma unroll
  for (int ks = 0; ks < 2; ++ks)
    qf[ks] = *(const bf16x8*)&qrow[(size_t)(qbase + lr) * HD_ + ks * 32 + lg * 8];
  f32x4 o[4] = {};
  float mrun = -INFINITY, lrun = 0.f;
  for (int kt = 0; kt < T_ / 64; ++kt) {
    int kvb = kt * 64;
    f32x4 st[4];
    #pragma unroll
    for (int kb4 = 0; kb4 < 4; ++kb4) {
      st[kb4] = (f32x4){0.f, 0.f, 0.f, 0.f};
      #pragma unroll
      for (int ks = 0; ks < 2; ++ks) {
        bf16x8 a = *(const bf16x8*)
            &krow[(size_t)(kvb + kb4 * 16 + lr) * HD_ + ks * 32 + lg * 8];
        st[kb4] = __builtin_amdgcn_mfma_f32_16x16x32_bf16(a, qf[ks], st[kb4], 0, 0, 0);
      }
    }
    // online softmax over kv (rows of St): reduce over regs then lg groups
    float mx = -INFINITY;
    #pragma unroll
    for (int kb4 = 0; kb4 < 4; ++kb4)
      #pragma unroll
      for (int r = 0; r < 4; ++r) mx = fmaxf(mx, st[kb4][r]);
    mx = fmaxf(mx, __shfl_xor(mx, 16));
    mx = fmaxf(mx, __shfl_xor(mx, 32));
    float mnew = fmaxf(mrun, mx);
    float scale = __expf(mrun - mnew);
    float ls = 0.f;
    #pragma unroll
    for (int kb4 = 0; kb4 < 4; ++kb4) {
      float p0 = __expf(st[kb4][0] - mnew);
      float p1 = __expf(st[kb4][1] - mnew);
      float p2 = __expf(st[kb4][2] - mnew);
      float p3 = __expf(st[kb4][3] - mnew);
      ls += p0 + p1 + p2 + p3;
      uint2 u;
      u.x = (u32)f2bf(p0) | ((u32)f2bf(p1) << 16);
      u.y = (u32)f2bf(p2) | ((u32)f2bf(p3) << 16);
      *(uint2*)&Pl[w][lr][PSW(lr, kb4 * 16 + lg * 4)] = u;
    }
    ls += __shfl_xor(ls, 16);
    ls += __shfl_xor(ls, 32);
    lrun = lrun * scale + ls;
    mrun = mnew;
    #pragma unroll
    for (int db = 0; db < 4; ++db) o[db] *= scale;
    __syncthreads();
    #pragma unroll
    for (int ks = 0; ks < 2; ++ks) {
      bf16x8 pf = *(const bf16x8*)&Pl[w][lr][PSW(lr, ks * 32 + lg * 8)];
      #pragma unroll
      for (int db = 0; db < 4; ++db) {
        bf16x8 vf = *(const bf16x8*)
            &vrow[(size_t)(db * 16 + lr) * T_ + kvb + ks * 32 + lg * 8];
        o[db] = __builtin_amdgcn_mfma_f32_16x16x32_bf16(vf, pf, o[db], 0, 0, 0);
      }
    }
    __syncthreads();
  }
  float inv = 1.f / lrun;
  int bb = bh >> 4, h = bh & 15;
  int m = (qbase + lr) * 2 + bb;
  #pragma unroll
  for (int db = 0; db < 4; ++db) {
    uint2 u;
    u.x = (u32)f2bf(o[db][0] * inv) | ((u32)f2bf(o[db][1] * inv) << 16);
    u.y = (u32)f2bf(o[db][2] * inv) | ((u32)f2bf(o[db][3] * inv) << 16);
    *(uint2*)&attnb[(size_t)m * E_ + h * 64 + db * 16 + lg * 4] = u;
  }
}

// ---------------- Pass E: out projection GEMM ------------------------------
// out[m][n] = sum_e A[m][e] * W[n][e] + bias[n],  fp32 out
__global__ __launch_bounds__(256) void gemm_out(
    const u16* __restrict__ A, const u16* __restrict__ W,
    const float* __restrict__ bias, float* __restrict__ out) {
  const int K = E_;
  __shared__ u16 As[128 * 32];
  __shared__ u16 Bs[128 * 32];
  const int tm = blockIdx.x * 128, tn = blockIdx.y * 128;
  const int tid = threadIdx.x;
  const int w = tid >> 6, lane = tid & 63, lr = lane & 15, lg = lane >> 4;
  const int wm = (w >> 1) * 64, wn = (w & 1) * 64;
  f32x4 acc[4][4] = {};
  for (int k0 = 0; k0 < K; k0 += 32) {
    #pragma unroll
    for (int hh = 0; hh < 2; ++hh) {
      int ca = (w * 2 + hh) * 64 + lane;
      gl_lds16(A + (size_t)(tm + (ca >> 2)) * K + k0 + (ca & 3) * 8,
               &As[(w * 2 + hh) * 512]);
      gl_lds16(W + (size_t)(tn + (ca >> 2)) * K + k0 + (ca & 3) * 8,
               &Bs[(w * 2 + hh) * 512]);
    }
    __syncthreads();
    bf16x8 af[4], bq[4];
    #pragma unroll
    for (int mi = 0; mi < 4; ++mi)
      af[mi] = *(const bf16x8*)&As[(wm + mi * 16 + lr) * 32 + lg * 8];
    #pragma unroll
    for (int ni = 0; ni < 4; ++ni)
      bq[ni] = *(const bf16x8*)&Bs[(wn + ni * 16 + lr) * 32 + lg * 8];
    #pragma unroll
    for (int mi = 0; mi < 4; ++mi)
      #pragma unroll
      for (int ni = 0; ni < 4; ++ni)
        acc[mi][ni] = __builtin_amdgcn_mfma_f32_16x16x32_bf16(
            af[mi], bq[ni], acc[mi][ni], 0, 0, 0);
    __syncthreads();
  }
  #pragma unroll
  for (int ni = 0; ni < 4; ++ni) {
    int n = tn + wn + ni * 16 + lr;
    float bv = bias[n];
    #pragma unroll
    for (int mi = 0; mi < 4; ++mi) {
      #pragma unroll
      for (int r = 0; r < 4; ++r) {
        int m = tm + wm + mi * 16 + lg * 4 + r;
        out[(size_t)m * E_ + n] = acc[mi][ni][r] + bv;
      }
    }
  }
}

// ---------------- launch ----------------------------------------------------
extern "C" void kernel_launch(void* const* d_in, const int* in_sizes, int n_in,
                              void* d_out, int out_size, void* d_ws, size_t ws_size,
                              hipStream_t stream) {
  const float* q   = (const float*)d_in[0];
  const float* rel = (const float*)d_in[1];
  const float* wi  = (const float*)d_in[2];
  const float* bi  = (const float*)d_in[3];
  const float* wo  = (const float*)d_in[4];
  const float* bo  = (const float*)d_in[5];
  float* out = (float*)d_out;
  char* ws = (char*)d_ws;
  // ws layout (bytes), 48 MiB total:
  u16* Xb  = (u16*)(ws);                    //  8 MiB  [4096][1024]
  u16* Wib = (u16*)(ws + 8388608);          //  6 MiB  [3072][1024]
  u16* Wob = (u16*)(ws + 14680064);         //  2 MiB  [1024][1024]
  u16* qb  = (u16*)(ws + 16777216);         //  8 MiB  [32][2048][64]
  u16* kb  = (u16*)(ws + 25165824);         //  8 MiB
  u16* vr  = (u16*)(ws + 33554432);         //  8 MiB
  u16* vt  = (u16*)(ws + 41943040);         //  8 MiB  [32][64][2048]
  u16* attnb = Xb;                          // overlay: X dead after gemm_qkv

  cvt_kernel<<<dim3(8192), dim3(256), 0, stream>>>(q, wi, wo, Xb, Wib, Wob);
  gemm_qkv<<<dim3(32, 24), dim3(256), 0, stream>>>(Xb, Wib, bi, rel, qb, kb, vr);
  vtrans<<<dim3(32, 32), dim3(256), 0, stream>>>(vr, vt);
  attn_kernel<<<dim3(32, 32), dim3(256), 0, stream>>>(qb, kb, vt, attnb);
  gemm_out<<<dim3(32, 8), dim3(256), 0, stream>>>(attnb, Wob, bo, out);
}

// Round 2
// 320.460 us; speedup vs baseline: 1.0091x; 1.0091x over previous
//
#include <hip/hip_runtime.h>

// Roformer MHA: T=2048 B=2 E=1024 H=16 HD=64
#define T_  2048
#define B_  2
#define E_  1024
#define H_  16
#define HD_ 64
#define M_  4096          // T*B rows
#define N_QKV 3072        // 3*E

typedef unsigned short u16;
typedef unsigned int   u32;
typedef __attribute__((ext_vector_type(8))) __bf16 bf16x8;
typedef __attribute__((ext_vector_type(4))) float  f32x4;

__device__ inline u16 f2bf(float f) {
  u32 u = __float_as_uint(f);
  u += 0x7fffu + ((u >> 16) & 1u);   // RTNE (finite values)
  return (u16)(u >> 16);
}

__device__ inline void gl_lds16(const u16* g, u16* l) {
  __builtin_amdgcn_global_load_lds(
      (const __attribute__((address_space(1))) u32*)g,
      (__attribute__((address_space(3))) u32*)l, 16, 0, 0);
}

// ---------------- Pass A: fp32 -> bf16 conversion --------------------------
__global__ __launch_bounds__(256) void cvt_kernel(
    const float* __restrict__ q, const float* __restrict__ wi,
    const float* __restrict__ wo, u16* __restrict__ X,
    u16* __restrict__ Wi, u16* __restrict__ Wo) {
  int idx = blockIdx.x * 256 + threadIdx.x;       // one float4 per thread
  const int n1 = (M_ * E_) / 4, n2 = (3 * E_ * E_) / 4;
  const float4* src; u16* dst; int i;
  if (idx < n1)            { src = (const float4*)q;  dst = X;  i = idx; }
  else if (idx < n1 + n2)  { src = (const float4*)wi; dst = Wi; i = idx - n1; }
  else                     { src = (const float4*)wo; dst = Wo; i = idx - n1 - n2; }
  float4 v = src[i];
  uint2 o;
  o.x = (u32)f2bf(v.x) | ((u32)f2bf(v.y) << 16);
  o.y = (u32)f2bf(v.z) | ((u32)f2bf(v.w) << 16);
  *(uint2*)&dst[(size_t)i * 4] = o;
}

// ---------------- Pass B: QKV GEMM + bias + scale + RoPE + scatter ---------
// C[m][n] = sum_e X[m][e] * W[n][e],  M=4096, N=3072, K=1024
__global__ __launch_bounds__(256) void gemm_qkv(
    const u16* __restrict__ X, const u16* __restrict__ W,
    const float* __restrict__ bias, const float* __restrict__ rel,
    u16* __restrict__ qb, u16* __restrict__ kb, u16* __restrict__ vr) {
  const int K = E_;
  __shared__ u16 As[128 * 32];
  __shared__ u16 Bs[128 * 32];
  const int tm = blockIdx.x * 128, tn = blockIdx.y * 128;
  const int tid = threadIdx.x;
  const int w = tid >> 6, lane = tid & 63, lr = lane & 15, lg = lane >> 4;
  const int wm = (w >> 1) * 64, wn = (w & 1) * 64;
  f32x4 acc[4][4] = {};
  for (int k0 = 0; k0 < K; k0 += 32) {
    #pragma unroll
    for (int hh = 0; hh < 2; ++hh) {
      int ca = (w * 2 + hh) * 64 + lane;           // 16B chunk index 0..511
      gl_lds16(X + (size_t)(tm + (ca >> 2)) * K + k0 + (ca & 3) * 8,
               &As[(w * 2 + hh) * 512]);
      gl_lds16(W + (size_t)(tn + (ca >> 2)) * K + k0 + (ca & 3) * 8,
               &Bs[(w * 2 + hh) * 512]);
    }
    __syncthreads();
    bf16x8 af[4], bq[4];
    #pragma unroll
    for (int mi = 0; mi < 4; ++mi)
      af[mi] = *(const bf16x8*)&As[(wm + mi * 16 + lr) * 32 + lg * 8];
    #pragma unroll
    for (int ni = 0; ni < 4; ++ni)
      bq[ni] = *(const bf16x8*)&Bs[(wn + ni * 16 + lr) * 32 + lg * 8];
    #pragma unroll
    for (int mi = 0; mi < 4; ++mi)
      #pragma unroll
      for (int ni = 0; ni < 4; ++ni)
        acc[mi][ni] = __builtin_amdgcn_mfma_f32_16x16x32_bf16(
            af[mi], bq[ni], acc[mi][ni], 0, 0, 0);
    __syncthreads();
  }
  // epilogue: bias, q-scale, RoPE(q,k), scatter to [bh][t][hd]
  #pragma unroll
  for (int ni = 0; ni < 4; ++ni) {
    int n = tn + wn + ni * 16 + lr;
    float bv = bias[n];
    int sect = n >> 10, nn = n & 1023;
    int h = nn >> 6, d = nn & 63, i2 = d >> 1;
    u16* dst = (sect == 0) ? qb : (sect == 1) ? kb : vr;
    #pragma unroll
    for (int mi = 0; mi < 4; ++mi) {
      #pragma unroll
      for (int r = 0; r < 4; ++r) {
        int m = tm + wm + mi * 16 + lg * 4 + r;
        int t = m >> 1, bb = m & 1;
        float v = acc[mi][ni][r] + bv;
        if (sect == 0) v *= 0.125f;                 // HD^-0.5
        if (sect < 2) {                             // RoPE (uniform branch)
          float partner = __shfl_xor(v, 1);
          float sp = rel[t * HD_ + i2];
          float cp = rel[t * HD_ + 32 + i2];
          float rot = (d & 1) ? partner : -partner;
          v = v * cp + rot * sp;
        }
        dst[((size_t)(bb * H_ + h) * T_ + t) * HD_ + d] = f2bf(v);
      }
    }
  }
}

// ---------------- Pass C: V transpose [bh][t][d] -> [bh][d][t] -------------
__global__ __launch_bounds__(256) void vtrans(
    const u16* __restrict__ vr, u16* __restrict__ vt) {
  __shared__ u16 tile[64][80];
  int bh = blockIdx.y, t0 = blockIdx.x * 64;
  int tid = threadIdx.x;
  int row = tid >> 2, c0 = (tid & 3) * 16;
  const u16* src = vr + ((size_t)bh * T_ + t0) * HD_;
  uint4 a = *(const uint4*)&src[row * HD_ + c0];
  uint4 b = *(const uint4*)&src[row * HD_ + c0 + 8];
  *(uint4*)&tile[row][c0] = a;
  *(uint4*)&tile[row][c0 + 8] = b;
  __syncthreads();
  int dr = tid >> 2, tc = (tid & 3) * 16;
  __align__(16) u16 vals[16];
  #pragma unroll
  for (int i = 0; i < 16; ++i) vals[i] = tile[tc + i][dr];
  u16* dstp = vt + ((size_t)bh * HD_ + dr) * T_ + t0 + tc;
  *(uint4*)&dstp[0] = *(uint4*)&vals[0];
  *(uint4*)&dstp[8] = *(uint4*)&vals[8];
}

// ---------------- Pass D: flash attention ----------------------------------
// grid (T/64, BH); 4 waves, each owns 16 q rows.
// Swapped QK^T: St = mfma(K, Q^T) so softmax row is reduced over lg groups.
// P staging buffer is PER-WAVE -> no __syncthreads needed at all.
// Row pad +8 elems (144B stride -> bank step 4 -> 2-way aliasing = free).
__global__ __launch_bounds__(256) void attn_kernel(
    const u16* __restrict__ qbm, const u16* __restrict__ kbm,
    const u16* __restrict__ vtm, u16* __restrict__ attnb) {
  int bh = blockIdx.y;
  int tid = threadIdx.x;
  int w = tid >> 6, lane = tid & 63, lr = lane & 15, lg = lane >> 4;
  int qbase = blockIdx.x * 64 + w * 16;
  __shared__ u16 Pl[4][16][72];
  const u16* qrow = qbm + (size_t)bh * T_ * HD_;
  const u16* krow = kbm + (size_t)bh * T_ * HD_;
  const u16* vrow = vtm + (size_t)bh * HD_ * T_;
  bf16x8 qf[2];
  #pragma unroll
  for (int ks = 0; ks < 2; ++ks)
    qf[ks] = *(const bf16x8*)&qrow[(size_t)(qbase + lr) * HD_ + ks * 32 + lg * 8];
  f32x4 o[4] = {};
  float mrun = -INFINITY, lrun = 0.f;
  for (int kt = 0; kt < T_ / 64; ++kt) {
    int kvb = kt * 64;
    f32x4 st[4];
    #pragma unroll
    for (int kb4 = 0; kb4 < 4; ++kb4) {
      st[kb4] = (f32x4){0.f, 0.f, 0.f, 0.f};
      #pragma unroll
      for (int ks = 0; ks < 2; ++ks) {
        bf16x8 a = *(const bf16x8*)
            &krow[(size_t)(kvb + kb4 * 16 + lr) * HD_ + ks * 32 + lg * 8];
        st[kb4] = __builtin_amdgcn_mfma_f32_16x16x32_bf16(a, qf[ks], st[kb4], 0, 0, 0);
      }
    }
    // V fragments: independent of softmax -> issue early, consume after.
    bf16x8 vf[2][4];
    #pragma unroll
    for (int ks = 0; ks < 2; ++ks)
      #pragma unroll
      for (int db = 0; db < 4; ++db)
        vf[ks][db] = *(const bf16x8*)
            &vrow[(size_t)(db * 16 + lr) * T_ + kvb + ks * 32 + lg * 8];
    // online softmax over kv (rows of St): reduce regs then lg groups
    float mx = -INFINITY;
    #pragma unroll
    for (int kb4 = 0; kb4 < 4; ++kb4)
      #pragma unroll
      for (int r = 0; r < 4; ++r) mx = fmaxf(mx, st[kb4][r]);
    mx = fmaxf(mx, __shfl_xor(mx, 16));
    mx = fmaxf(mx, __shfl_xor(mx, 32));
    // T13 defer-max: skip O/l rescale when max grew by <= 8 (wave-uniform)
    if (!__all(mx <= mrun + 8.f)) {
      float mnew = fmaxf(mrun, mx);
      float sc = __expf(mrun - mnew);
      lrun *= sc;
      #pragma unroll
      for (int db = 0; db < 4; ++db) o[db] *= sc;
      mrun = mnew;
    }
    float ls = 0.f;
    #pragma unroll
    for (int kb4 = 0; kb4 < 4; ++kb4) {
      float p0 = __expf(st[kb4][0] - mrun);
      float p1 = __expf(st[kb4][1] - mrun);
      float p2 = __expf(st[kb4][2] - mrun);
      float p3 = __expf(st[kb4][3] - mrun);
      ls += p0 + p1 + p2 + p3;
      uint2 u;
      u.x = (u32)f2bf(p0) | ((u32)f2bf(p1) << 16);
      u.y = (u32)f2bf(p2) | ((u32)f2bf(p3) << 16);
      *(uint2*)&Pl[w][lr][kb4 * 16 + lg * 4] = u;
    }
    ls += __shfl_xor(ls, 16);
    ls += __shfl_xor(ls, 32);
    lrun += ls;
    #pragma unroll
    for (int ks = 0; ks < 2; ++ks) {
      bf16x8 pf = *(const bf16x8*)&Pl[w][lr][ks * 32 + lg * 8];
      #pragma unroll
      for (int db = 0; db < 4; ++db)
        o[db] = __builtin_amdgcn_mfma_f32_16x16x32_bf16(vf[ks][db], pf, o[db], 0, 0, 0);
    }
  }
  float inv = 1.f / lrun;
  int bb = bh >> 4, h = bh & 15;
  int m = (qbase + lr) * 2 + bb;
  #pragma unroll
  for (int db = 0; db < 4; ++db) {
    uint2 u;
    u.x = (u32)f2bf(o[db][0] * inv) | ((u32)f2bf(o[db][1] * inv) << 16);
    u.y = (u32)f2bf(o[db][2] * inv) | ((u32)f2bf(o[db][3] * inv) << 16);
    *(uint2*)&attnb[(size_t)m * E_ + h * 64 + db * 16 + lg * 4] = u;
  }
}

// ---------------- Pass E: out projection GEMM ------------------------------
// out[m][n] = sum_e A[m][e] * W[n][e] + bias[n],  fp32 out
__global__ __launch_bounds__(256) void gemm_out(
    const u16* __restrict__ A, const u16* __restrict__ W,
    const float* __restrict__ bias, float* __restrict__ out) {
  const int K = E_;
  __shared__ u16 As[128 * 32];
  __shared__ u16 Bs[128 * 32];
  const int tm = blockIdx.x * 128, tn = blockIdx.y * 128;
  const int tid = threadIdx.x;
  const int w = tid >> 6, lane = tid & 63, lr = lane & 15, lg = lane >> 4;
  const int wm = (w >> 1) * 64, wn = (w & 1) * 64;
  f32x4 acc[4][4] = {};
  for (int k0 = 0; k0 < K; k0 += 32) {
    #pragma unroll
    for (int hh = 0; hh < 2; ++hh) {
      int ca = (w * 2 + hh) * 64 + lane;
      gl_lds16(A + (size_t)(tm + (ca >> 2)) * K + k0 + (ca & 3) * 8,
               &As[(w * 2 + hh) * 512]);
      gl_lds16(W + (size_t)(tn + (ca >> 2)) * K + k0 + (ca & 3) * 8,
               &Bs[(w * 2 + hh) * 512]);
    }
    __syncthreads();
    bf16x8 af[4], bq[4];
    #pragma unroll
    for (int mi = 0; mi < 4; ++mi)
      af[mi] = *(const bf16x8*)&As[(wm + mi * 16 + lr) * 32 + lg * 8];
    #pragma unroll
    for (int ni = 0; ni < 4; ++ni)
      bq[ni] = *(const bf16x8*)&Bs[(wn + ni * 16 + lr) * 32 + lg * 8];
    #pragma unroll
    for (int mi = 0; mi < 4; ++mi)
      #pragma unroll
      for (int ni = 0; ni < 4; ++ni)
        acc[mi][ni] = __builtin_amdgcn_mfma_f32_16x16x32_bf16(
            af[mi], bq[ni], acc[mi][ni], 0, 0, 0);
    __syncthreads();
  }
  #pragma unroll
  for (int ni = 0; ni < 4; ++ni) {
    int n = tn + wn + ni * 16 + lr;
    float bv = bias[n];
    #pragma unroll
    for (int mi = 0; mi < 4; ++mi) {
      #pragma unroll
      for (int r = 0; r < 4; ++r) {
        int m = tm + wm + mi * 16 + lg * 4 + r;
        out[(size_t)m * E_ + n] = acc[mi][ni][r] + bv;
      }
    }
  }
}

// ---------------- launch ----------------------------------------------------
extern "C" void kernel_launch(void* const* d_in, const int* in_sizes, int n_in,
                              void* d_out, int out_size, void* d_ws, size_t ws_size,
                              hipStream_t stream) {
  const float* q   = (const float*)d_in[0];
  const float* rel = (const float*)d_in[1];
  const float* wi  = (const float*)d_in[2];
  const float* bi  = (const float*)d_in[3];
  const float* wo  = (const float*)d_in[4];
  const float* bo  = (const float*)d_in[5];
  float* out = (float*)d_out;
  char* ws = (char*)d_ws;
  // ws layout (bytes), 48 MiB total:
  u16* Xb  = (u16*)(ws);                    //  8 MiB  [4096][1024]
  u16* Wib = (u16*)(ws + 8388608);          //  6 MiB  [3072][1024]
  u16* Wob = (u16*)(ws + 14680064);         //  2 MiB  [1024][1024]
  u16* qb  = (u16*)(ws + 16777216);         //  8 MiB  [32][2048][64]
  u16* kb  = (u16*)(ws + 25165824);         //  8 MiB
  u16* vr  = (u16*)(ws + 33554432);         //  8 MiB
  u16* vt  = (u16*)(ws + 41943040);         //  8 MiB  [32][64][2048]
  u16* attnb = Xb;                          // overlay: X dead after gemm_qkv

  cvt_kernel<<<dim3(8192), dim3(256), 0, stream>>>(q, wi, wo, Xb, Wib, Wob);
  gemm_qkv<<<dim3(32, 24), dim3(256), 0, stream>>>(Xb, Wib, bi, rel, qb, kb, vr);
  vtrans<<<dim3(32, 32), dim3(256), 0, stream>>>(vr, vt);
  attn_kernel<<<dim3(32, 32), dim3(256), 0, stream>>>(qb, kb, vt, attnb);
  gemm_out<<<dim3(32, 8), dim3(256), 0, stream>>>(attnb, Wob, bo, out);
}

// Round 3
// 159.611 us; speedup vs baseline: 2.0261x; 2.0077x over previous
//
#include <hip/hip_runtime.h>

// Roformer MHA: T=2048 B=2 E=1024 H=16 HD=64
#define T_  2048
#define B_  2
#define E_  1024
#define H_  16
#define HD_ 64
#define M_  4096          // T*B rows
#define N_QKV 3072        // 3*E

typedef unsigned short u16;
typedef unsigned int   u32;
typedef __attribute__((ext_vector_type(8))) __bf16 bf16x8;
typedef __attribute__((ext_vector_type(4))) float  f32x4;

__device__ inline u16 f2bf(float f) {
  u32 u = __float_as_uint(f);
  u += 0x7fffu + ((u >> 16) & 1u);   // RTNE (finite values)
  return (u16)(u >> 16);
}

__device__ inline void gl_lds16(const u16* g, u16* l) {
  __builtin_amdgcn_global_load_lds(
      (const __attribute__((address_space(1))) u32*)g,
      (__attribute__((address_space(3))) u32*)l, 16, 0, 0);
}

// ---------------- Pass A: fp32 -> bf16 conversion --------------------------
__global__ __launch_bounds__(256) void cvt_kernel(
    const float* __restrict__ q, const float* __restrict__ wi,
    const float* __restrict__ wo, u16* __restrict__ X,
    u16* __restrict__ Wi, u16* __restrict__ Wo) {
  int idx = blockIdx.x * 256 + threadIdx.x;       // one float4 per thread
  const int n1 = (M_ * E_) / 4, n2 = (3 * E_ * E_) / 4;
  const float4* src; u16* dst; int i;
  if (idx < n1)            { src = (const float4*)q;  dst = X;  i = idx; }
  else if (idx < n1 + n2)  { src = (const float4*)wi; dst = Wi; i = idx - n1; }
  else                     { src = (const float4*)wo; dst = Wo; i = idx - n1 - n2; }
  float4 v = src[i];
  uint2 o;
  o.x = (u32)f2bf(v.x) | ((u32)f2bf(v.y) << 16);
  o.y = (u32)f2bf(v.z) | ((u32)f2bf(v.w) << 16);
  *(uint2*)&dst[(size_t)i * 4] = o;
}

// ---------------- Pass B: QKV GEMM + bias + scale + RoPE + scatter ---------
// C[m][n] = sum_e X[m][e] * W[n][e],  M=4096, N=3072, K=1024
// K and V are written PRE-PERMUTED into fragment-major kv-tile order so the
// attention kernel can stage them with contiguous global_load_lds.
__global__ __launch_bounds__(256) void gemm_qkv(
    const u16* __restrict__ X, const u16* __restrict__ W,
    const float* __restrict__ bias, const float* __restrict__ rel,
    u16* __restrict__ qb, u16* __restrict__ kp, u16* __restrict__ vp) {
  const int K = E_;
  __shared__ u16 As[128 * 32];
  __shared__ u16 Bs[128 * 32];
  const int tm = blockIdx.x * 128, tn = blockIdx.y * 128;
  const int tid = threadIdx.x;
  const int w = tid >> 6, lane = tid & 63, lr = lane & 15, lg = lane >> 4;
  const int wm = (w >> 1) * 64, wn = (w & 1) * 64;
  f32x4 acc[4][4] = {};
  for (int k0 = 0; k0 < K; k0 += 32) {
    #pragma unroll
    for (int hh = 0; hh < 2; ++hh) {
      int ca = (w * 2 + hh) * 64 + lane;           // 16B chunk index 0..511
      gl_lds16(X + (size_t)(tm + (ca >> 2)) * K + k0 + (ca & 3) * 8,
               &As[(w * 2 + hh) * 512]);
      gl_lds16(W + (size_t)(tn + (ca >> 2)) * K + k0 + (ca & 3) * 8,
               &Bs[(w * 2 + hh) * 512]);
    }
    __syncthreads();
    bf16x8 af[4], bq[4];
    #pragma unroll
    for (int mi = 0; mi < 4; ++mi)
      af[mi] = *(const bf16x8*)&As[(wm + mi * 16 + lr) * 32 + lg * 8];
    #pragma unroll
    for (int ni = 0; ni < 4; ++ni)
      bq[ni] = *(const bf16x8*)&Bs[(wn + ni * 16 + lr) * 32 + lg * 8];
    #pragma unroll
    for (int mi = 0; mi < 4; ++mi)
      #pragma unroll
      for (int ni = 0; ni < 4; ++ni)
        acc[mi][ni] = __builtin_amdgcn_mfma_f32_16x16x32_bf16(
            af[mi], bq[ni], acc[mi][ni], 0, 0, 0);
    __syncthreads();
  }
  // epilogue: bias, q-scale, RoPE(q,k), scatter
  #pragma unroll
  for (int ni = 0; ni < 4; ++ni) {
    int n = tn + wn + ni * 16 + lr;
    float bv = bias[n];
    int sect = n >> 10, nn = n & 1023;
    int h = nn >> 6, d = nn & 63, i2 = d >> 1;
    #pragma unroll
    for (int mi = 0; mi < 4; ++mi) {
      #pragma unroll
      for (int r = 0; r < 4; ++r) {
        int m = tm + wm + mi * 16 + lg * 4 + r;
        int t = m >> 1, bb = m & 1;
        float v = acc[mi][ni][r] + bv;
        if (sect == 0) v *= 0.125f;                 // HD^-0.5
        if (sect < 2) {                             // RoPE (uniform branch)
          float partner = __shfl_xor(v, 1);
          float sp = rel[t * HD_ + i2];
          float cp = rel[t * HD_ + 32 + i2];
          float rot = (d & 1) ? partner : -partner;
          v = v * cp + rot * sp;
        }
        int bh = bb * H_ + h;
        u16 val = f2bf(v);
        if (sect == 0) {
          qb[((size_t)bh * T_ + t) * HD_ + d] = val;
        } else if (sect == 1) {
          // K fragment-major: tile (bh, t>>6); kv=t&63
          // idx = ((kv>>4)*2+(d>>5))*512 + ((d>>3)&3)*128 + (kv&15)*8 + (d&7)
          int kv = t & 63;
          kp[(((size_t)bh * 32 + (t >> 6)) << 12)
             + (((kv >> 4) * 2 + (d >> 5)) << 9)
             + (((d >> 3) & 3) << 7) + ((kv & 15) << 3) + (d & 7)] = val;
        } else {
          // V^T fragment-major: tile (bh, t>>6); tl=t&63
          // idx = ((tl>>5)*4+(d>>4))*512 + ((tl>>3)&3)*128 + (d&15)*8 + (tl&7)
          int tl = t & 63;
          vp[(((size_t)bh * 32 + (t >> 6)) << 12)
             + (((tl >> 5) * 4 + (d >> 4)) << 9)
             + (((tl >> 3) & 3) << 7) + ((d & 15) << 3) + (tl & 7)] = val;
        }
      }
    }
  }
}

// ---------------- Pass D: flash attention ----------------------------------
// grid (T/64, BH); 4 waves, each owns 16 q rows.
// K/V tiles staged to LDS from fragment-major kp/vp (contiguous gl_lds),
// double-buffered; all fragment reads are contiguous ds_read_b128.
__global__ __launch_bounds__(256, 4) void attn_kernel(
    const u16* __restrict__ qbm, const u16* __restrict__ kp,
    const u16* __restrict__ vp, u16* __restrict__ attnb) {
  __shared__ u16 Kl[2][4096];                 // 2 x 8KB
  __shared__ u16 Vl[2][4096];                 // 2 x 8KB
  __shared__ u16 Pl[4][1024];                 // per-wave 2KB, fragment-major
  int bh = blockIdx.y;
  int tid = threadIdx.x;
  int w = tid >> 6, lane = tid & 63, lr = lane & 15, lg = lane >> 4;
  int qbase = blockIdx.x * 64 + w * 16;
  const u16* qrow  = qbm + (size_t)bh * T_ * HD_;
  const u16* ktile = kp + ((size_t)bh * 32) * 4096;
  const u16* vtile = vp + ((size_t)bh * 32) * 4096;
  bf16x8 qf[2];
  #pragma unroll
  for (int ks = 0; ks < 2; ++ks)
    qf[ks] = *(const bf16x8*)&qrow[(size_t)(qbase + lr) * HD_ + ks * 32 + lg * 8];
  const int cb0 = w * 128, cb1 = w * 128 + 64;
  // prologue: stage tile 0 into buf 0
  gl_lds16(ktile + (size_t)(cb0 + lane) * 8, &Kl[0][cb0 * 8]);
  gl_lds16(ktile + (size_t)(cb1 + lane) * 8, &Kl[0][cb1 * 8]);
  gl_lds16(vtile + (size_t)(cb0 + lane) * 8, &Vl[0][cb0 * 8]);
  gl_lds16(vtile + (size_t)(cb1 + lane) * 8, &Vl[0][cb1 * 8]);
  f32x4 o[4] = {};
  float mrun = -INFINITY, lrun = 0.f;
  __syncthreads();
  for (int kt = 0; kt < 32; ++kt) {
    int cur = kt & 1;
    if (kt < 31) {                           // stage next tile into other buf
      const u16* kn = ktile + ((size_t)(kt + 1)) * 4096;
      const u16* vn = vtile + ((size_t)(kt + 1)) * 4096;
      gl_lds16(kn + (size_t)(cb0 + lane) * 8, &Kl[cur ^ 1][cb0 * 8]);
      gl_lds16(kn + (size_t)(cb1 + lane) * 8, &Kl[cur ^ 1][cb1 * 8]);
      gl_lds16(vn + (size_t)(cb0 + lane) * 8, &Vl[cur ^ 1][cb0 * 8]);
      gl_lds16(vn + (size_t)(cb1 + lane) * 8, &Vl[cur ^ 1][cb1 * 8]);
    }
    // QK^T (swapped): St[kv][q]
    f32x4 st[4];
    #pragma unroll
    for (int kb4 = 0; kb4 < 4; ++kb4) {
      st[kb4] = (f32x4){0.f, 0.f, 0.f, 0.f};
      #pragma unroll
      for (int ks = 0; ks < 2; ++ks) {
        bf16x8 a = *(const bf16x8*)&Kl[cur][(kb4 * 2 + ks) * 512 + lane * 8];
        st[kb4] = __builtin_amdgcn_mfma_f32_16x16x32_bf16(a, qf[ks], st[kb4], 0, 0, 0);
      }
    }
    // online softmax (reduce regs then lg groups)
    float mx = -INFINITY;
    #pragma unroll
    for (int kb4 = 0; kb4 < 4; ++kb4)
      #pragma unroll
      for (int r = 0; r < 4; ++r) mx = fmaxf(mx, st[kb4][r]);
    mx = fmaxf(mx, __shfl_xor(mx, 16));
    mx = fmaxf(mx, __shfl_xor(mx, 32));
    if (!__all(mx <= mrun + 8.f)) {          // T13 defer-max rescale
      float mnew = fmaxf(mrun, mx);
      float sc = __expf(mrun - mnew);
      lrun *= sc;
      #pragma unroll
      for (int db = 0; db < 4; ++db) o[db] *= sc;
      mrun = mnew;
    }
    float ls = 0.f;
    #pragma unroll
    for (int kb4 = 0; kb4 < 4; ++kb4) {
      float p0 = __expf(st[kb4][0] - mrun);
      float p1 = __expf(st[kb4][1] - mrun);
      float p2 = __expf(st[kb4][2] - mrun);
      float p3 = __expf(st[kb4][3] - mrun);
      ls += p0 + p1 + p2 + p3;
      uint2 u;
      u.x = (u32)f2bf(p0) | ((u32)f2bf(p1) << 16);
      u.y = (u32)f2bf(p2) | ((u32)f2bf(p3) << 16);
      // fragment-major P: elem (kv,q) at (kv>>3)*128 + q*8 + (kv&7)
      *(uint2*)&Pl[w][((kb4 * 2 + (lg >> 1)) << 7) + (lr << 3) + ((lg & 1) << 2)] = u;
    }
    ls += __shfl_xor(ls, 16);
    ls += __shfl_xor(ls, 32);
    lrun += ls;
    // PV: contiguous pf + vf reads
    #pragma unroll
    for (int ks = 0; ks < 2; ++ks) {
      bf16x8 pf = *(const bf16x8*)&Pl[w][ks * 512 + lane * 8];
      #pragma unroll
      for (int db = 0; db < 4; ++db) {
        bf16x8 vf = *(const bf16x8*)&Vl[cur][(ks * 4 + db) * 512 + lane * 8];
        o[db] = __builtin_amdgcn_mfma_f32_16x16x32_bf16(vf, pf, o[db], 0, 0, 0);
      }
    }
    __syncthreads();                         // drains vmcnt: next tile ready
  }
  float inv = 1.f / lrun;
  int bb = bh >> 4, h = bh & 15;
  int m = (qbase + lr) * 2 + bb;
  #pragma unroll
  for (int db = 0; db < 4; ++db) {
    uint2 u;
    u.x = (u32)f2bf(o[db][0] * inv) | ((u32)f2bf(o[db][1] * inv) << 16);
    u.y = (u32)f2bf(o[db][2] * inv) | ((u32)f2bf(o[db][3] * inv) << 16);
    *(uint2*)&attnb[(size_t)m * E_ + h * 64 + db * 16 + lg * 4] = u;
  }
}

// ---------------- Pass E: out projection GEMM ------------------------------
// out[m][n] = sum_e A[m][e] * W[n][e] + bias[n],  fp32 out
__global__ __launch_bounds__(256) void gemm_out(
    const u16* __restrict__ A, const u16* __restrict__ W,
    const float* __restrict__ bias, float* __restrict__ out) {
  const int K = E_;
  __shared__ u16 As[128 * 32];
  __shared__ u16 Bs[128 * 32];
  const int tm = blockIdx.x * 128, tn = blockIdx.y * 128;
  const int tid = threadIdx.x;
  const int w = tid >> 6, lane = tid & 63, lr = lane & 15, lg = lane >> 4;
  const int wm = (w >> 1) * 64, wn = (w & 1) * 64;
  f32x4 acc[4][4] = {};
  for (int k0 = 0; k0 < K; k0 += 32) {
    #pragma unroll
    for (int hh = 0; hh < 2; ++hh) {
      int ca = (w * 2 + hh) * 64 + lane;
      gl_lds16(A + (size_t)(tm + (ca >> 2)) * K + k0 + (ca & 3) * 8,
               &As[(w * 2 + hh) * 512]);
      gl_lds16(W + (size_t)(tn + (ca >> 2)) * K + k0 + (ca & 3) * 8,
               &Bs[(w * 2 + hh) * 512]);
    }
    __syncthreads();
    bf16x8 af[4], bq[4];
    #pragma unroll
    for (int mi = 0; mi < 4; ++mi)
      af[mi] = *(const bf16x8*)&As[(wm + mi * 16 + lr) * 32 + lg * 8];
    #pragma unroll
    for (int ni = 0; ni < 4; ++ni)
      bq[ni] = *(const bf16x8*)&Bs[(wn + ni * 16 + lr) * 32 + lg * 8];
    #pragma unroll
    for (int mi = 0; mi < 4; ++mi)
      #pragma unroll
      for (int ni = 0; ni < 4; ++ni)
        acc[mi][ni] = __builtin_amdgcn_mfma_f32_16x16x32_bf16(
            af[mi], bq[ni], acc[mi][ni], 0, 0, 0);
    __syncthreads();
  }
  #pragma unroll
  for (int ni = 0; ni < 4; ++ni) {
    int n = tn + wn + ni * 16 + lr;
    float bv = bias[n];
    #pragma unroll
    for (int mi = 0; mi < 4; ++mi) {
      #pragma unroll
      for (int r = 0; r < 4; ++r) {
        int m = tm + wm + mi * 16 + lg * 4 + r;
        out[(size_t)m * E_ + n] = acc[mi][ni][r] + bv;
      }
    }
  }
}

// ---------------- launch ----------------------------------------------------
extern "C" void kernel_launch(void* const* d_in, const int* in_sizes, int n_in,
                              void* d_out, int out_size, void* d_ws, size_t ws_size,
                              hipStream_t stream) {
  const float* q   = (const float*)d_in[0];
  const float* rel = (const float*)d_in[1];
  const float* wi  = (const float*)d_in[2];
  const float* bi  = (const float*)d_in[3];
  const float* wo  = (const float*)d_in[4];
  const float* bo  = (const float*)d_in[5];
  float* out = (float*)d_out;
  char* ws = (char*)d_ws;
  // ws layout (bytes), 40 MiB total:
  u16* Xb  = (u16*)(ws);                    //  8 MiB  [4096][1024]
  u16* Wib = (u16*)(ws + 8388608);          //  6 MiB  [3072][1024]
  u16* Wob = (u16*)(ws + 14680064);         //  2 MiB  [1024][1024]
  u16* qb  = (u16*)(ws + 16777216);         //  8 MiB  [32][2048][64]
  u16* kpb = (u16*)(ws + 25165824);         //  8 MiB  [32][32][4096] frag-major
  u16* vpb = (u16*)(ws + 33554432);         //  8 MiB  [32][32][4096] frag-major
  u16* attnb = Xb;                          // overlay: X dead after gemm_qkv

  cvt_kernel<<<dim3(8192), dim3(256), 0, stream>>>(q, wi, wo, Xb, Wib, Wob);
  gemm_qkv<<<dim3(32, 24), dim3(256), 0, stream>>>(Xb, Wib, bi, rel, qb, kpb, vpb);
  attn_kernel<<<dim3(32, 32), dim3(256), 0, stream>>>(qb, kpb, vpb, attnb);
  gemm_out<<<dim3(32, 8), dim3(256), 0, stream>>>(attnb, Wob, bo, out);
}

// Round 4
// 153.885 us; speedup vs baseline: 2.1015x; 1.0372x over previous
//
#include <hip/hip_runtime.h>

// Roformer MHA: T=2048 B=2 E=1024 H=16 HD=64
#define T_  2048
#define B_  2
#define E_  1024
#define H_  16
#define HD_ 64
#define M_  4096          // T*B rows
#define N_QKV 3072        // 3*E

typedef unsigned short u16;
typedef unsigned int   u32;
typedef __attribute__((ext_vector_type(8))) __bf16 bf16x8;
typedef __attribute__((ext_vector_type(4))) float  f32x4;

__device__ inline u16 f2bf(float f) {
  u32 u = __float_as_uint(f);
  u += 0x7fffu + ((u >> 16) & 1u);   // RTNE (finite values)
  return (u16)(u >> 16);
}

__device__ inline void gl_lds16(const u16* g, u16* l) {
  __builtin_amdgcn_global_load_lds(
      (const __attribute__((address_space(1))) u32*)g,
      (__attribute__((address_space(3))) u32*)l, 16, 0, 0);
}

// T1: bijective XCD-aware block swizzle (requires nwg % 8 == 0)
__device__ inline int xcd_swz(int orig, int nwg) {
  return (orig & 7) * (nwg >> 3) + (orig >> 3);
}

// ---------------- Pass A: fp32 -> bf16 conversion --------------------------
__global__ __launch_bounds__(256) void cvt_kernel(
    const float* __restrict__ q, const float* __restrict__ wi,
    const float* __restrict__ wo, u16* __restrict__ X,
    u16* __restrict__ Wi, u16* __restrict__ Wo) {
  int idx = blockIdx.x * 256 + threadIdx.x;       // one float4 per thread
  const int n1 = (M_ * E_) / 4, n2 = (3 * E_ * E_) / 4;
  const float4* src; u16* dst; int i;
  if (idx < n1)            { src = (const float4*)q;  dst = X;  i = idx; }
  else if (idx < n1 + n2)  { src = (const float4*)wi; dst = Wi; i = idx - n1; }
  else                     { src = (const float4*)wo; dst = Wo; i = idx - n1 - n2; }
  float4 v = src[i];
  uint2 o;
  o.x = (u32)f2bf(v.x) | ((u32)f2bf(v.y) << 16);
  o.y = (u32)f2bf(v.z) | ((u32)f2bf(v.w) << 16);
  *(uint2*)&dst[(size_t)i * 4] = o;
}

// ---------------- Pass B: QKV GEMM + bias + scale + RoPE + scatter ---------
// C[m][n] = sum_e X[m][e] * W[n][e],  M=4096, N=3072, K=1024
// 2-phase double-buffered K-loop (T3 minimum recipe): stage t+1 before
// computing t, one barrier per iter. K/V written fragment-major for attn.
__global__ __launch_bounds__(256) void gemm_qkv(
    const u16* __restrict__ X, const u16* __restrict__ W,
    const float* __restrict__ bias, const float* __restrict__ rel,
    u16* __restrict__ qb, u16* __restrict__ kp, u16* __restrict__ vp) {
  const int K = E_;
  __shared__ u16 As[2][4096];
  __shared__ u16 Bs[2][4096];
  int orig = blockIdx.y * gridDim.x + blockIdx.x;
  int wgid = xcd_swz(orig, 32 * 24);
  const int tm = (wgid & 31) * 128, tn = (wgid >> 5) * 128;
  const int tid = threadIdx.x;
  const int w = tid >> 6, lane = tid & 63, lr = lane & 15, lg = lane >> 4;
  const int wm = (w >> 1) * 64, wn = (w & 1) * 64;
  auto stage = [&](int buf, int k0) {
    #pragma unroll
    for (int hh = 0; hh < 2; ++hh) {
      int ca = (w * 2 + hh) * 64 + lane;           // 16B chunk index 0..511
      gl_lds16(X + (size_t)(tm + (ca >> 2)) * K + k0 + (ca & 3) * 8,
               &As[buf][(w * 2 + hh) * 512]);
      gl_lds16(W + (size_t)(tn + (ca >> 2)) * K + k0 + (ca & 3) * 8,
               &Bs[buf][(w * 2 + hh) * 512]);
    }
  };
  f32x4 acc[4][4] = {};
  stage(0, 0);
  __syncthreads();
  for (int it = 0; it < 32; ++it) {
    int cur = it & 1;
    if (it < 31) stage(cur ^ 1, (it + 1) * 32);
    bf16x8 af[4], bq[4];
    #pragma unroll
    for (int mi = 0; mi < 4; ++mi)
      af[mi] = *(const bf16x8*)&As[cur][(wm + mi * 16 + lr) * 32 + lg * 8];
    #pragma unroll
    for (int ni = 0; ni < 4; ++ni)
      bq[ni] = *(const bf16x8*)&Bs[cur][(wn + ni * 16 + lr) * 32 + lg * 8];
    #pragma unroll
    for (int mi = 0; mi < 4; ++mi)
      #pragma unroll
      for (int ni = 0; ni < 4; ++ni)
        acc[mi][ni] = __builtin_amdgcn_mfma_f32_16x16x32_bf16(
            af[mi], bq[ni], acc[mi][ni], 0, 0, 0);
    __syncthreads();                    // drains stage loads; cur reads done
  }
  // epilogue: bias, q-scale, RoPE(q,k), scatter
  #pragma unroll
  for (int ni = 0; ni < 4; ++ni) {
    int n = tn + wn + ni * 16 + lr;
    float bv = bias[n];
    int sect = n >> 10, nn = n & 1023;
    int h = nn >> 6, d = nn & 63, i2 = d >> 1;
    #pragma unroll
    for (int mi = 0; mi < 4; ++mi) {
      #pragma unroll
      for (int r = 0; r < 4; ++r) {
        int m = tm + wm + mi * 16 + lg * 4 + r;
        int t = m >> 1, bb = m & 1;
        float v = acc[mi][ni][r] + bv;
        if (sect == 0) v *= 0.125f;                 // HD^-0.5
        if (sect < 2) {                             // RoPE (uniform branch)
          float partner = __shfl_xor(v, 1);
          float sp = rel[t * HD_ + i2];
          float cp = rel[t * HD_ + 32 + i2];
          float rot = (d & 1) ? partner : -partner;
          v = v * cp + rot * sp;
        }
        int bh = bb * H_ + h;
        u16 val = f2bf(v);
        if (sect == 0) {
          qb[((size_t)bh * T_ + t) * HD_ + d] = val;
        } else if (sect == 1) {
          // K fragment-major: tile (bh, t>>6); kv=t&63
          int kv = t & 63;
          kp[(((size_t)bh * 32 + (t >> 6)) << 12)
             + (((kv >> 4) * 2 + (d >> 5)) << 9)
             + (((d >> 3) & 3) << 7) + ((kv & 15) << 3) + (d & 7)] = val;
        } else {
          // V^T fragment-major: tile (bh, t>>6); tl=t&63
          int tl = t & 63;
          vp[(((size_t)bh * 32 + (t >> 6)) << 12)
             + (((tl >> 5) * 4 + (d >> 4)) << 9)
             + (((tl >> 3) & 3) << 7) + ((d & 15) << 3) + (tl & 7)] = val;
        }
      }
    }
  }
}

// ---------------- Pass D: flash attention ----------------------------------
// grid (T/64, BH); 4 waves, each owns 16 q rows.
// K/V tiles staged to LDS from fragment-major kp/vp (contiguous gl_lds),
// double-buffered; all fragment reads are contiguous ds_read_b128.
__global__ __launch_bounds__(256, 4) void attn_kernel(
    const u16* __restrict__ qbm, const u16* __restrict__ kp,
    const u16* __restrict__ vp, u16* __restrict__ attnb) {
  __shared__ u16 Kl[2][4096];                 // 2 x 8KB
  __shared__ u16 Vl[2][4096];                 // 2 x 8KB
  __shared__ u16 Pl[4][1024];                 // per-wave 2KB, fragment-major
  int orig = blockIdx.y * gridDim.x + blockIdx.x;
  int wgid = xcd_swz(orig, 32 * 32);
  int bh = wgid >> 5;
  int tid = threadIdx.x;
  int w = tid >> 6, lane = tid & 63, lr = lane & 15, lg = lane >> 4;
  int qbase = (wgid & 31) * 64 + w * 16;
  const u16* qrow  = qbm + (size_t)bh * T_ * HD_;
  const u16* ktile = kp + ((size_t)bh * 32) * 4096;
  const u16* vtile = vp + ((size_t)bh * 32) * 4096;
  bf16x8 qf[2];
  #pragma unroll
  for (int ks = 0; ks < 2; ++ks)
    qf[ks] = *(const bf16x8*)&qrow[(size_t)(qbase + lr) * HD_ + ks * 32 + lg * 8];
  const int cb0 = w * 128, cb1 = w * 128 + 64;
  // prologue: stage tile 0 into buf 0
  gl_lds16(ktile + (size_t)(cb0 + lane) * 8, &Kl[0][cb0 * 8]);
  gl_lds16(ktile + (size_t)(cb1 + lane) * 8, &Kl[0][cb1 * 8]);
  gl_lds16(vtile + (size_t)(cb0 + lane) * 8, &Vl[0][cb0 * 8]);
  gl_lds16(vtile + (size_t)(cb1 + lane) * 8, &Vl[0][cb1 * 8]);
  f32x4 o[4] = {};
  float mrun = -INFINITY, lrun = 0.f;
  __syncthreads();
  for (int kt = 0; kt < 32; ++kt) {
    int cur = kt & 1;
    if (kt < 31) {                           // stage next tile into other buf
      const u16* kn = ktile + ((size_t)(kt + 1)) * 4096;
      const u16* vn = vtile + ((size_t)(kt + 1)) * 4096;
      gl_lds16(kn + (size_t)(cb0 + lane) * 8, &Kl[cur ^ 1][cb0 * 8]);
      gl_lds16(kn + (size_t)(cb1 + lane) * 8, &Kl[cur ^ 1][cb1 * 8]);
      gl_lds16(vn + (size_t)(cb0 + lane) * 8, &Vl[cur ^ 1][cb0 * 8]);
      gl_lds16(vn + (size_t)(cb1 + lane) * 8, &Vl[cur ^ 1][cb1 * 8]);
    }
    // QK^T (swapped): St[kv][q]
    f32x4 st[4];
    #pragma unroll
    for (int kb4 = 0; kb4 < 4; ++kb4) {
      st[kb4] = (f32x4){0.f, 0.f, 0.f, 0.f};
      #pragma unroll
      for (int ks = 0; ks < 2; ++ks) {
        bf16x8 a = *(const bf16x8*)&Kl[cur][(kb4 * 2 + ks) * 512 + lane * 8];
        st[kb4] = __builtin_amdgcn_mfma_f32_16x16x32_bf16(a, qf[ks], st[kb4], 0, 0, 0);
      }
    }
    // online softmax (reduce regs then lg groups)
    float mx = -INFINITY;
    #pragma unroll
    for (int kb4 = 0; kb4 < 4; ++kb4)
      #pragma unroll
      for (int r = 0; r < 4; ++r) mx = fmaxf(mx, st[kb4][r]);
    mx = fmaxf(mx, __shfl_xor(mx, 16));
    mx = fmaxf(mx, __shfl_xor(mx, 32));
    if (!__all(mx <= mrun + 8.f)) {          // T13 defer-max rescale
      float mnew = fmaxf(mrun, mx);
      float sc = __expf(mrun - mnew);
      lrun *= sc;
      #pragma unroll
      for (int db = 0; db < 4; ++db) o[db] *= sc;
      mrun = mnew;
    }
    float ls = 0.f;
    #pragma unroll
    for (int kb4 = 0; kb4 < 4; ++kb4) {
      float p0 = __expf(st[kb4][0] - mrun);
      float p1 = __expf(st[kb4][1] - mrun);
      float p2 = __expf(st[kb4][2] - mrun);
      float p3 = __expf(st[kb4][3] - mrun);
      ls += p0 + p1 + p2 + p3;
      uint2 u;
      u.x = (u32)f2bf(p0) | ((u32)f2bf(p1) << 16);
      u.y = (u32)f2bf(p2) | ((u32)f2bf(p3) << 16);
      // fragment-major P: elem (kv,q) at (kv>>3)*128 + q*8 + (kv&7)
      *(uint2*)&Pl[w][((kb4 * 2 + (lg >> 1)) << 7) + (lr << 3) + ((lg & 1) << 2)] = u;
    }
    ls += __shfl_xor(ls, 16);
    ls += __shfl_xor(ls, 32);
    lrun += ls;
    // PV: contiguous pf + vf reads
    #pragma unroll
    for (int ks = 0; ks < 2; ++ks) {
      bf16x8 pf = *(const bf16x8*)&Pl[w][ks * 512 + lane * 8];
      #pragma unroll
      for (int db = 0; db < 4; ++db) {
        bf16x8 vf = *(const bf16x8*)&Vl[cur][(ks * 4 + db) * 512 + lane * 8];
        o[db] = __builtin_amdgcn_mfma_f32_16x16x32_bf16(vf, pf, o[db], 0, 0, 0);
      }
    }
    __syncthreads();                         // drains vmcnt: next tile ready
  }
  float inv = 1.f / lrun;
  int bb = bh >> 4, h = bh & 15;
  int m = (qbase + lr) * 2 + bb;
  #pragma unroll
  for (int db = 0; db < 4; ++db) {
    uint2 u;
    u.x = (u32)f2bf(o[db][0] * inv) | ((u32)f2bf(o[db][1] * inv) << 16);
    u.y = (u32)f2bf(o[db][2] * inv) | ((u32)f2bf(o[db][3] * inv) << 16);
    *(uint2*)&attnb[(size_t)m * E_ + h * 64 + db * 16 + lg * 4] = u;
  }
}

// ---------------- Pass E: out projection GEMM ------------------------------
// out[m][n] = sum_e A[m][e] * W[n][e] + bias[n],  fp32 out; 2-phase dbuf
__global__ __launch_bounds__(256) void gemm_out(
    const u16* __restrict__ A, const u16* __restrict__ W,
    const float* __restrict__ bias, float* __restrict__ out) {
  const int K = E_;
  __shared__ u16 As[2][4096];
  __shared__ u16 Bs[2][4096];
  int orig = blockIdx.y * gridDim.x + blockIdx.x;
  int wgid = xcd_swz(orig, 32 * 8);
  const int tm = (wgid & 31) * 128, tn = (wgid >> 5) * 128;
  const int tid = threadIdx.x;
  const int w = tid >> 6, lane = tid & 63, lr = lane & 15, lg = lane >> 4;
  const int wm = (w >> 1) * 64, wn = (w & 1) * 64;
  auto stage = [&](int buf, int k0) {
    #pragma unroll
    for (int hh = 0; hh < 2; ++hh) {
      int ca = (w * 2 + hh) * 64 + lane;
      gl_lds16(A + (size_t)(tm + (ca >> 2)) * K + k0 + (ca & 3) * 8,
               &As[buf][(w * 2 + hh) * 512]);
      gl_lds16(W + (size_t)(tn + (ca >> 2)) * K + k0 + (ca & 3) * 8,
               &Bs[buf][(w * 2 + hh) * 512]);
    }
  };
  f32x4 acc[4][4] = {};
  stage(0, 0);
  __syncthreads();
  for (int it = 0; it < 32; ++it) {
    int cur = it & 1;
    if (it < 31) stage(cur ^ 1, (it + 1) * 32);
    bf16x8 af[4], bq[4];
    #pragma unroll
    for (int mi = 0; mi < 4; ++mi)
      af[mi] = *(const bf16x8*)&As[cur][(wm + mi * 16 + lr) * 32 + lg * 8];
    #pragma unroll
    for (int ni = 0; ni < 4; ++ni)
      bq[ni] = *(const bf16x8*)&Bs[cur][(wn + ni * 16 + lr) * 32 + lg * 8];
    #pragma unroll
    for (int mi = 0; mi < 4; ++mi)
      #pragma unroll
      for (int ni = 0; ni < 4; ++ni)
        acc[mi][ni] = __builtin_amdgcn_mfma_f32_16x16x32_bf16(
            af[mi], bq[ni], acc[mi][ni], 0, 0, 0);
    __syncthreads();
  }
  #pragma unroll
  for (int ni = 0; ni < 4; ++ni) {
    int n = tn + wn + ni * 16 + lr;
    float bv = bias[n];
    #pragma unroll
    for (int mi = 0; mi < 4; ++mi) {
      #pragma unroll
      for (int r = 0; r < 4; ++r) {
        int m = tm + wm + mi * 16 + lg * 4 + r;
        out[(size_t)m * E_ + n] = acc[mi][ni][r] + bv;
      }
    }
  }
}

// ---------------- launch ----------------------------------------------------
extern "C" void kernel_launch(void* const* d_in, const int* in_sizes, int n_in,
                              void* d_out, int out_size, void* d_ws, size_t ws_size,
                              hipStream_t stream) {
  const float* q   = (const float*)d_in[0];
  const float* rel = (const float*)d_in[1];
  const float* wi  = (const float*)d_in[2];
  const float* bi  = (const float*)d_in[3];
  const float* wo  = (const float*)d_in[4];
  const float* bo  = (const float*)d_in[5];
  float* out = (float*)d_out;
  char* ws = (char*)d_ws;
  // ws layout (bytes), 40 MiB total:
  u16* Xb  = (u16*)(ws);                    //  8 MiB  [4096][1024]
  u16* Wib = (u16*)(ws + 8388608);          //  6 MiB  [3072][1024]
  u16* Wob = (u16*)(ws + 14680064);         //  2 MiB  [1024][1024]
  u16* qb  = (u16*)(ws + 16777216);         //  8 MiB  [32][2048][64]
  u16* kpb = (u16*)(ws + 25165824);         //  8 MiB  [32][32][4096] frag-major
  u16* vpb = (u16*)(ws + 33554432);         //  8 MiB  [32][32][4096] frag-major
  u16* attnb = Xb;                          // overlay: X dead after gemm_qkv

  cvt_kernel<<<dim3(8192), dim3(256), 0, stream>>>(q, wi, wo, Xb, Wib, Wob);
  gemm_qkv<<<dim3(32, 24), dim3(256), 0, stream>>>(Xb, Wib, bi, rel, qb, kpb, vpb);
  attn_kernel<<<dim3(32, 32), dim3(256), 0, stream>>>(qb, kpb, vpb, attnb);
  gemm_out<<<dim3(32, 8), dim3(256), 0, stream>>>(attnb, Wob, bo, out);
}